// Round 7
// baseline (159.409 us; speedup 1.0000x reference)
//
#include <hip/hip_runtime.h>
#include <hip/hip_bf16.h>

// Problem dims (fixed by reference)
constexpr int Bb = 8;
constexpr int Dd = 64;
constexpr int Tt = 8192;
constexpr int Kk = 1024;
constexpr int BT = Bb * Tt;            // 65536 rows
constexpr int NTOT = Bb * Dd * Tt;     // 4194304 elements

// Output layout (float32): [codes BT][quantized NTOT][loss 1]
constexpr int OUT_Q_OFF = BT;
constexpr int OUT_LOSS_OFF = BT + NTOT;

// Workspace layout (bytes)
constexpr size_t WS_CODES_OFF = 0;                      // int32[BT]
constexpr size_t WS_PREC_OFF  = (size_t)BT * 4;         // float[K]
constexpr size_t WS_PART_OFF  = WS_PREC_OFF + Kk * 4;   // float[256]

// ---------------- Kernel P: prec[k] = ||e_k||^2 ----------------
__global__ void __launch_bounds__(256) prec_kernel(const float* __restrict__ cb,
                                                   float* __restrict__ prec) {
    int k = blockIdx.x * 256 + threadIdx.x;
    if (k < Kk) {
        const float4* row = reinterpret_cast<const float4*>(cb + (size_t)k * Dd);
        float s = 0.f;
#pragma unroll
        for (int i = 0; i < 16; ++i) {
            float4 v = row[i];
            s = fmaf(v.x, v.x, s); s = fmaf(v.y, v.y, s);
            s = fmaf(v.z, v.z, s); s = fmaf(v.w, v.w, s);
        }
        prec[k] = s;
    }
}

// ---------------- Kernel A: argmin over K ----------------
// 64 rows per block (one per lane), 4 waves split K within staged chunks.
// Score replicates the reference's fp32 evaluation ORDER so that its
// magnitude-64 quantization (ulp ~7.6e-6) and resulting argmin ties match:
//   t1  = fp32( zsq + esq[k] )        // numpy's (A + B), rounded once
//   s_k = fp32( t1 - 2*dot_k )        // numpy's  ... - 2.0*C, one more rounding -> fmaf
// Ties (equal fp32 scores) resolve to the LOWEST k, matching np.argmin.
//
// Register-pressure history: r3 bare lb -> VGPR 64; r4 lb(256,4) -> VGPR 60;
// r6 + asm pin -> still 60, dur unchanged. Diagnosis: the kk+=4 body's PEAK
// live set (~135 regs) exceeds the 128 budget, so the allocator demotes the
// whole 64-float z-row (rematerializes from global inside the K loop).
// Fix here: kk+=2 body -> live set ~97 < 128. Pin stays to forbid remat.
constexpr int ROWS_PB = 64;
constexpr int SPLITS = 4;     // waves per block
constexpr int CHUNK = 128;    // codebook rows staged per iteration
constexpr int KPW = CHUNK / SPLITS;  // 32 k's per wave per chunk

__global__ void __launch_bounds__(256, 4) argmin_kernel(
    const float* __restrict__ z, const float* __restrict__ cb,
    const float* __restrict__ prec, float* __restrict__ out,
    int* __restrict__ codes_i)
{
    __shared__ float lds_e[CHUNK * Dd];   // 32 KiB
    __shared__ float lds_p[CHUNK];
    __shared__ float s_best[SPLITS][ROWS_PB];
    __shared__ int   s_bidx[SPLITS][ROWS_PB];

    const int tid = threadIdx.x;
    const int rl = tid & 63;      // lane = row within block
    const int sp = tid >> 6;      // wave = K-split
    const int row = blockIdx.x * ROWS_PB + rl;
    const int b = row >> 13;      // T = 8192
    const int t = row & (Tt - 1);
    const float* zrow = z + (size_t)b * (Dd * Tt) + t;

    // z row into registers (coalesced across lanes for each d)
    float zr[Dd];
#pragma unroll
    for (int d = 0; d < Dd; ++d) zr[d] = zrow[(size_t)d * Tt];

    // PIN: forbid rematerialization of the loaded row (scalar "+v" only;
    // float4 operands are rejected as tied indirect inputs).
#pragma unroll
    for (int g = 0; g < 4; ++g) {
        asm volatile("" :
            "+v"(zr[g*16+0]),  "+v"(zr[g*16+1]),  "+v"(zr[g*16+2]),  "+v"(zr[g*16+3]),
            "+v"(zr[g*16+4]),  "+v"(zr[g*16+5]),  "+v"(zr[g*16+6]),  "+v"(zr[g*16+7]),
            "+v"(zr[g*16+8]),  "+v"(zr[g*16+9]),  "+v"(zr[g*16+10]), "+v"(zr[g*16+11]),
            "+v"(zr[g*16+12]), "+v"(zr[g*16+13]), "+v"(zr[g*16+14]), "+v"(zr[g*16+15]));
    }

    // ||z||^2 in fp32. Exact numpy bit-match NOT required: any fp32 result in
    // the same binade differs from numpy's by an exact grid multiple, which
    // shifts all d[k] equally through the rounding -> argmin/ties preserved.
    float zsq = 0.f;
#pragma unroll
    for (int d = 0; d < Dd; ++d) zsq = fmaf(zr[d], zr[d], zsq);

    float best = 3.4e38f;
    int bidx = 0;

    for (int c = 0; c < Kk; c += CHUNK) {
        __syncthreads();
        // stage CHUNK*64 floats, coalesced
        const float4* src = reinterpret_cast<const float4*>(cb + (size_t)c * Dd);
        float4* dst = reinterpret_cast<float4*>(lds_e);
#pragma unroll
        for (int i = 0; i < (CHUNK * Dd / 4) / 256; ++i)   // 8 iters
            dst[tid + i * 256] = src[tid + i * 256];
        if (tid < CHUNK) lds_p[tid] = prec[c + tid];
        __syncthreads();

        // this wave's k range within the chunk, ascending; 2 k's per iter
        // (narrow body keeps peak live regs under the 128 budget)
        const int k0base = sp * KPW;
        for (int kk = k0base; kk < k0base + KPW; kk += 2) {
            const float4* e0 = reinterpret_cast<const float4*>(lds_e + (kk + 0) * Dd);
            const float4* e1 = reinterpret_cast<const float4*>(lds_e + (kk + 1) * Dd);
            float a0 = 0.f, a1 = 0.f;
#pragma unroll
            for (int d4 = 0; d4 < 16; ++d4) {
                float4 va = e0[d4], vb = e1[d4];
                const float z0 = zr[4 * d4 + 0], z1 = zr[4 * d4 + 1];
                const float z2 = zr[4 * d4 + 2], z3 = zr[4 * d4 + 3];
                a0 = fmaf(va.x, z0, a0); a0 = fmaf(va.y, z1, a0);
                a0 = fmaf(va.z, z2, a0); a0 = fmaf(va.w, z3, a0);
                a1 = fmaf(vb.x, z0, a1); a1 = fmaf(vb.y, z1, a1);
                a1 = fmaf(vb.z, z2, a1); a1 = fmaf(vb.w, z3, a1);
            }
            // Reference-order fp32: t1 = round(zsq + esq), s = round(t1 - 2*dot)
            const float t10 = zsq + lds_p[kk + 0];
            const float t11 = zsq + lds_p[kk + 1];
            const float s0 = fmaf(-2.f, a0, t10);
            const float s1 = fmaf(-2.f, a1, t11);
            const int kg = c + kk;
            if (s0 < best) { best = s0; bidx = kg + 0; }
            if (s1 < best) { best = s1; bidx = kg + 1; }
        }
    }

    s_best[sp][rl] = best;
    s_bidx[sp][rl] = bidx;
    __syncthreads();
    if (sp == 0) {
#pragma unroll
        for (int s = 1; s < SPLITS; ++s) {
            const float ob = s_best[s][rl];
            const int oi = s_bidx[s][rl];
            if (ob < best || (ob == best && oi < bidx)) { best = ob; bidx = oi; }
        }
        codes_i[row] = bidx;
        out[row] = (float)bidx;
    }
}

// ---------------- Kernel B: quantized + loss partials ----------------
__global__ void __launch_bounds__(256) quant_kernel(
    const float* __restrict__ z, const float* __restrict__ cb,
    const int* __restrict__ codes_i, float* __restrict__ out,
    float* __restrict__ partials)
{
    const int row = blockIdx.x * 256 + threadIdx.x;  // grid = 256 blocks
    const int b = row >> 13;
    const int t = row & (Tt - 1);
    const int code = codes_i[row];
    const float4* crow = reinterpret_cast<const float4*>(cb + (size_t)code * Dd);
    const float* zbase = z + (size_t)b * (Dd * Tt) + t;
    float* obase = out + OUT_Q_OFF + (size_t)b * (Dd * Tt) + t;

    float acc = 0.f;
#pragma unroll
    for (int d4 = 0; d4 < 16; ++d4) {
        float4 v = crow[d4];
        float vv[4] = {v.x, v.y, v.z, v.w};
#pragma unroll
        for (int j = 0; j < 4; ++j) {
            const int d = d4 * 4 + j;
            const float zv = zbase[(size_t)d * Tt];
            const float diff = vv[j] - zv;
            acc = fmaf(diff, diff, acc);
            obase[(size_t)d * Tt] = vv[j];
        }
    }

    __shared__ float red[256];
    red[threadIdx.x] = acc;
    __syncthreads();
#pragma unroll
    for (int s = 128; s > 0; s >>= 1) {
        if (threadIdx.x < s) red[threadIdx.x] += red[threadIdx.x + s];
        __syncthreads();
    }
    if (threadIdx.x == 0) partials[blockIdx.x] = red[0];
}

// ---------------- Kernel C: final loss reduce ----------------
__global__ void __launch_bounds__(256) loss_kernel(const float* __restrict__ partials,
                                                   float* __restrict__ out) {
    __shared__ float red[256];
    red[threadIdx.x] = partials[threadIdx.x];  // exactly 256 partials
    __syncthreads();
#pragma unroll
    for (int s = 128; s > 0; s >>= 1) {
        if (threadIdx.x < s) red[threadIdx.x] += red[threadIdx.x + s];
        __syncthreads();
    }
    if (threadIdx.x == 0)
        out[OUT_LOSS_OFF] = red[0] * (1.0f / (float)NTOT);
}

extern "C" void kernel_launch(void* const* d_in, const int* in_sizes, int n_in,
                              void* d_out, int out_size, void* d_ws, size_t ws_size,
                              hipStream_t stream) {
    const float* z = (const float*)d_in[0];
    const float* cb = (const float*)d_in[1];
    float* out = (float*)d_out;

    char* ws = (char*)d_ws;
    int* codes_i = (int*)(ws + WS_CODES_OFF);
    float* prec = (float*)(ws + WS_PREC_OFF);
    float* partials = (float*)(ws + WS_PART_OFF);

    prec_kernel<<<(Kk + 255) / 256, 256, 0, stream>>>(cb, prec);
    argmin_kernel<<<BT / ROWS_PB, 256, 0, stream>>>(z, cb, prec, out, codes_i);
    quant_kernel<<<BT / 256, 256, 0, stream>>>(z, cb, codes_i, out, partials);
    loss_kernel<<<1, 256, 0, stream>>>(partials, out);
}

// Round 8
// 94.069 us; speedup vs baseline: 1.6946x; 1.6946x over previous
//
#include <hip/hip_runtime.h>
#include <hip/hip_bf16.h>

typedef __attribute__((ext_vector_type(8))) short short8;   // 8 bf16 = 4 VGPR
typedef __attribute__((ext_vector_type(4))) float f32x4;

// Problem dims (fixed by reference)
constexpr int Bb = 8;
constexpr int Dd = 64;
constexpr int Tt = 8192;
constexpr int Kk = 1024;
constexpr int BT = Bb * Tt;            // 65536 rows
constexpr int NTOT = Bb * Dd * Tt;     // 4194304 elements

// Output layout (float32): [codes BT][quantized NTOT][loss 1]
constexpr int OUT_Q_OFF = BT;
constexpr int OUT_LOSS_OFF = BT + NTOT;

// Workspace layout (bytes)
constexpr size_t WS_CODES_OFF = 0;                        // int32[BT]      256KB
constexpr size_t WS_PREC_OFF  = (size_t)BT * 4;           // float[K]       4KB
constexpr size_t WS_PART_OFF  = WS_PREC_OFF + 4096;       // float[256]     1KB
constexpr size_t WS_EH_OFF    = WS_PART_OFF + 4096;       // bf16[K*D]      128KB
constexpr size_t WS_EM_OFF    = WS_EH_OFF + (size_t)Kk * Dd * 2;
constexpr size_t WS_EL_OFF    = WS_EM_OFF + (size_t)Kk * Dd * 2;

// ---- bf16 helpers (RNE, matches numpy/jax) ----
__device__ inline ushort rne_bf16(float v) {
    unsigned u = __float_as_uint(v);
    return (ushort)((u + 0x7FFFu + ((u >> 16) & 1u)) >> 16);
}
__device__ inline float bf16f(ushort h) { return __uint_as_float(((unsigned)h) << 16); }

// ---------------- Kernel P: prec[k] = ||e_k||^2 (fp32, exact path) ----------------
__global__ void __launch_bounds__(256) prec_kernel(const float* __restrict__ cb,
                                                   float* __restrict__ prec) {
    int k = blockIdx.x * 256 + threadIdx.x;
    if (k < Kk) {
        const float4* row = reinterpret_cast<const float4*>(cb + (size_t)k * Dd);
        float s = 0.f;
#pragma unroll
        for (int i = 0; i < 16; ++i) {
            float4 v = row[i];
            s = fmaf(v.x, v.x, s); s = fmaf(v.y, v.y, s);
            s = fmaf(v.z, v.z, s); s = fmaf(v.w, v.w, s);
        }
        prec[k] = s;
    }
}

// ---------------- Kernel S: 3-way bf16 split of codebook ----------------
// e = eh + em + el + r, |r| <= 2^-27 |e|  (each sub exact by Sterbenz)
__global__ void __launch_bounds__(256) split_e_kernel(const float* __restrict__ cb,
                                                      ushort* __restrict__ eh,
                                                      ushort* __restrict__ em,
                                                      ushort* __restrict__ el) {
    int i = blockIdx.x * 256 + threadIdx.x;   // K*D = 65536 total
    float v = cb[i];
    ushort h = rne_bf16(v);  float hf = bf16f(h);
    float r1 = v - hf;       ushort m = rne_bf16(r1); float mf = bf16f(m);
    float r2 = r1 - mf;      ushort l = rne_bf16(r2);
    eh[i] = h; em[i] = m; el[i] = l;
}

// ---------------- Kernel A: fused split-MFMA GEMM + argmin ----------------
// Score = fp32(t1 - 2*dot), t1 = fp32(zsq + esq) — reference op order preserved.
// dot via 6 bf16 MFMA passes (zh,zm,zl x eh,em,el keeping weight >= 2^-18 terms),
// chained into one fp32 accumulator: error ~1e-9 == the fp32-VALU band that passes.
// Fragment model for v_mfma_f32_16x16x32_bf16:
//   A[row][k]: row = lane&15, k = (lane>>4)*8 + j  (8 contiguous bf16 = b128)
//   B[k][n]:   n  = lane&15, k = (lane>>4)*8 + j  (B stored [n][k] row-major)
//   C[row][n]: n  = lane&15, row = (lane>>4)*4 + reg   (m89-verified)
constexpr int TM = 64;              // rows per block
constexpr int TNK = 64;             // codebook entries per k-tile
constexpr int NKT = Kk / TNK;       // 16 tiles

__global__ void __launch_bounds__(256, 4) mfma_argmin_kernel(
    const float* __restrict__ z,
    const ushort* __restrict__ eh, const ushort* __restrict__ em,
    const ushort* __restrict__ el,
    const float* __restrict__ prec, float* __restrict__ out,
    int* __restrict__ codes_i)
{
    // swizzled bf16 tiles: [split][row][d], row stride 128B, byte ^= (row&7)<<4
    __shared__ __align__(16) ushort z_lds[3 * 64 * 64];   // 24 KB
    __shared__ __align__(16) ushort e_lds[3 * 64 * 64];   // 24 KB
    __shared__ float zsq_part[4][64];
    __shared__ float zsq_lds[64];
    __shared__ float esq_lds[64];
    float* bestv_lds = reinterpret_cast<float*>(z_lds);   // overlay after k-loop
    int*   besti_lds = reinterpret_cast<int*>(e_lds);     // overlay after k-loop

    const int tid = threadIdx.x;
    const int lane = tid & 63;
    const int w = tid >> 6;                 // wave 0..3 -> k-slice w*16..+16
    const int row0 = blockIdx.x * TM;       // global row base (row = b*T + t)
    const int b = row0 >> 13;
    const int t0 = row0 & (Tt - 1);

    // ---- stage z: read [d][t] coalesced, 3-way split, write transposed+swizzled
    {
        const int tt = tid & 63;            // row within tile
        const int dg = tid >> 6;            // d-group: d = dg*16 .. +16
        const float* zp = z + (size_t)b * (Dd * Tt) + (size_t)(dg * 16) * Tt + (t0 + tt);
        float vals[16];
        float psum = 0.f;
#pragma unroll
        for (int i = 0; i < 16; ++i) {
            float v = zp[(size_t)i * Tt];
            vals[i] = v;
            psum = fmaf(v, v, psum);
        }
        zsq_part[dg][tt] = psum;
#pragma unroll
        for (int g = 0; g < 2; ++g) {
            short8 hv, mv, lv;
#pragma unroll
            for (int j = 0; j < 8; ++j) {
                float v = vals[g * 8 + j];
                ushort h = rne_bf16(v);  float hf = bf16f(h);
                float r1 = v - hf;       ushort m = rne_bf16(r1); float mf = bf16f(m);
                float r2 = r1 - mf;      ushort l = rne_bf16(r2);
                hv[j] = (short)h; mv[j] = (short)m; lv[j] = (short)l;
            }
            const int byte_in_row = dg * 32 + g * 16;     // d0*2
            const int sw = tt * 128 + (byte_in_row ^ ((tt & 7) << 4));
            *reinterpret_cast<short8*>((char*)z_lds + 0 * 8192 + sw) = hv;
            *reinterpret_cast<short8*>((char*)z_lds + 1 * 8192 + sw) = mv;
            *reinterpret_cast<short8*>((char*)z_lds + 2 * 8192 + sw) = lv;
        }
    }
    __syncthreads();
    if (tid < 64)
        zsq_lds[tid] = ((zsq_part[0][tid] + zsq_part[1][tid]) + zsq_part[2][tid]) + zsq_part[3][tid];
    __syncthreads();

    // per-lane row set: row = rf*16 + (lane>>4)*4 + j
    float zsq_r[16];
#pragma unroll
    for (int rf = 0; rf < 4; ++rf)
#pragma unroll
        for (int j = 0; j < 4; ++j)
            zsq_r[rf * 4 + j] = zsq_lds[rf * 16 + (lane >> 4) * 4 + j];

    float bestv[16];
    int   besti[16];
#pragma unroll
    for (int i = 0; i < 16; ++i) { bestv[i] = 3.4e38f; besti[i] = 0; }

    for (int kt = 0; kt < NKT; ++kt) {
        __syncthreads();   // protect e_lds from previous tile's reads
        // ---- stage e k-tile (3 planes, 512 b128 chunks each, 2/thread/plane)
        {
            const ushort* srcs0 = eh; const ushort* srcs1 = em; const ushort* srcs2 = el;
#pragma unroll
            for (int r = 0; r < 2; ++r) {
                const int chunk = tid + r * 256;
                const int krow = chunk >> 3;
                const int d8 = (chunk & 7);
                const size_t gsrc = (size_t)(kt * 64 + krow) * 64 + d8 * 8;
                const int sw = krow * 128 + ((d8 * 16) ^ ((krow & 7) << 4));
                *reinterpret_cast<short8*>((char*)e_lds + 0 * 8192 + sw) =
                    *reinterpret_cast<const short8*>(srcs0 + gsrc);
                *reinterpret_cast<short8*>((char*)e_lds + 1 * 8192 + sw) =
                    *reinterpret_cast<const short8*>(srcs1 + gsrc);
                *reinterpret_cast<short8*>((char*)e_lds + 2 * 8192 + sw) =
                    *reinterpret_cast<const short8*>(srcs2 + gsrc);
            }
            if (tid < 64) esq_lds[tid] = prec[kt * 64 + tid];
        }
        __syncthreads();

        // ---- 6-pass MFMA: acc[rf] over (64 rows x this wave's 16 k)
        f32x4 acc[4];
#pragma unroll
        for (int rf = 0; rf < 4; ++rf) acc[rf] = (f32x4){0.f, 0.f, 0.f, 0.f};

#pragma unroll
        for (int dstep = 0; dstep < 2; ++dstep) {
            const int dby = dstep * 64 + ((lane >> 4) * 16);
            const int kr = w * 16 + (lane & 15);
            const int boff = kr * 128 + (dby ^ ((kr & 7) << 4));
            short8 B0 = *reinterpret_cast<const short8*>((char*)e_lds + 0 * 8192 + boff);
            short8 B1 = *reinterpret_cast<const short8*>((char*)e_lds + 1 * 8192 + boff);
            short8 B2 = *reinterpret_cast<const short8*>((char*)e_lds + 2 * 8192 + boff);
#pragma unroll
            for (int sA = 0; sA < 3; ++sA) {
                short8 A[4];
#pragma unroll
                for (int rf = 0; rf < 4; ++rf) {
                    const int row = rf * 16 + (lane & 15);
                    A[rf] = *reinterpret_cast<const short8*>(
                        (char*)z_lds + sA * 8192 + row * 128 + (dby ^ ((row & 7) << 4)));
                }
#pragma unroll
                for (int rf = 0; rf < 4; ++rf)
                    acc[rf] = __builtin_amdgcn_mfma_f32_16x16x32_bf16(A[rf], B0, acc[rf], 0, 0, 0);
                if (sA < 2) {
#pragma unroll
                    for (int rf = 0; rf < 4; ++rf)
                        acc[rf] = __builtin_amdgcn_mfma_f32_16x16x32_bf16(A[rf], B1, acc[rf], 0, 0, 0);
                }
                if (sA == 0) {
#pragma unroll
                    for (int rf = 0; rf < 4; ++rf)
                        acc[rf] = __builtin_amdgcn_mfma_f32_16x16x32_bf16(A[rf], B2, acc[rf], 0, 0, 0);
                }
            }
        }

        // ---- epilogue: score + running argmin (this lane's k is fixed = kglob)
        const int kglob = kt * 64 + w * 16 + (lane & 15);
        const float esql = esq_lds[w * 16 + (lane & 15)];
#pragma unroll
        for (int rf = 0; rf < 4; ++rf)
#pragma unroll
            for (int j = 0; j < 4; ++j) {
                const float t1 = zsq_r[rf * 4 + j] + esql;       // round(zsq+esq)
                const float s = fmaf(-2.f, acc[rf][j], t1);      // round(t1-2dot)
                if (s < bestv[rf * 4 + j]) { bestv[rf * 4 + j] = s; besti[rf * 4 + j] = kglob; }
            }
    }

    // ---- final cross-slot reduce via LDS overlay
    __syncthreads();
#pragma unroll
    for (int rf = 0; rf < 4; ++rf)
#pragma unroll
        for (int j = 0; j < 4; ++j) {
            const int row = rf * 16 + (lane >> 4) * 4 + j;
            const int slot = w * 16 + (lane & 15);
            bestv_lds[row * 64 + slot] = bestv[rf * 4 + j];
            besti_lds[row * 64 + slot] = besti[rf * 4 + j];
        }
    __syncthreads();
    if (tid < 64) {
        float bv = bestv_lds[tid * 64 + 0];
        int   bi = besti_lds[tid * 64 + 0];
        for (int s = 1; s < 64; ++s) {
            const float v = bestv_lds[tid * 64 + s];
            const int   i = besti_lds[tid * 64 + s];
            if (v < bv || (v == bv && i < bi)) { bv = v; bi = i; }
        }
        codes_i[row0 + tid] = bi;
        out[row0 + tid] = (float)bi;
    }
}

// ---------------- Kernel B: quantized + loss partials ----------------
__global__ void __launch_bounds__(256) quant_kernel(
    const float* __restrict__ z, const float* __restrict__ cb,
    const int* __restrict__ codes_i, float* __restrict__ out,
    float* __restrict__ partials)
{
    const int row = blockIdx.x * 256 + threadIdx.x;  // grid = 256 blocks
    const int b = row >> 13;
    const int t = row & (Tt - 1);
    const int code = codes_i[row];
    const float4* crow = reinterpret_cast<const float4*>(cb + (size_t)code * Dd);
    const float* zbase = z + (size_t)b * (Dd * Tt) + t;
    float* obase = out + OUT_Q_OFF + (size_t)b * (Dd * Tt) + t;

    float acc = 0.f;
#pragma unroll
    for (int d4 = 0; d4 < 16; ++d4) {
        float4 v = crow[d4];
        float vv[4] = {v.x, v.y, v.z, v.w};
#pragma unroll
        for (int j = 0; j < 4; ++j) {
            const int d = d4 * 4 + j;
            const float zv = zbase[(size_t)d * Tt];
            const float diff = vv[j] - zv;
            acc = fmaf(diff, diff, acc);
            obase[(size_t)d * Tt] = vv[j];
        }
    }

    __shared__ float red[256];
    red[threadIdx.x] = acc;
    __syncthreads();
#pragma unroll
    for (int s = 128; s > 0; s >>= 1) {
        if (threadIdx.x < s) red[threadIdx.x] += red[threadIdx.x + s];
        __syncthreads();
    }
    if (threadIdx.x == 0) partials[blockIdx.x] = red[0];
}

// ---------------- Kernel C: final loss reduce ----------------
__global__ void __launch_bounds__(256) loss_kernel(const float* __restrict__ partials,
                                                   float* __restrict__ out) {
    __shared__ float red[256];
    red[threadIdx.x] = partials[threadIdx.x];  // exactly 256 partials
    __syncthreads();
#pragma unroll
    for (int s = 128; s > 0; s >>= 1) {
        if (threadIdx.x < s) red[threadIdx.x] += red[threadIdx.x + s];
        __syncthreads();
    }
    if (threadIdx.x == 0)
        out[OUT_LOSS_OFF] = red[0] * (1.0f / (float)NTOT);
}

extern "C" void kernel_launch(void* const* d_in, const int* in_sizes, int n_in,
                              void* d_out, int out_size, void* d_ws, size_t ws_size,
                              hipStream_t stream) {
    const float* z = (const float*)d_in[0];
    const float* cb = (const float*)d_in[1];
    float* out = (float*)d_out;

    char* ws = (char*)d_ws;
    int* codes_i = (int*)(ws + WS_CODES_OFF);
    float* prec = (float*)(ws + WS_PREC_OFF);
    float* partials = (float*)(ws + WS_PART_OFF);
    ushort* eh = (ushort*)(ws + WS_EH_OFF);
    ushort* em = (ushort*)(ws + WS_EM_OFF);
    ushort* el = (ushort*)(ws + WS_EL_OFF);

    prec_kernel<<<(Kk + 255) / 256, 256, 0, stream>>>(cb, prec);
    split_e_kernel<<<(Kk * Dd) / 256, 256, 0, stream>>>(cb, eh, em, el);
    mfma_argmin_kernel<<<BT / TM, 256, 0, stream>>>(z, eh, em, el, prec, out, codes_i);
    quant_kernel<<<BT / 256, 256, 0, stream>>>(z, cb, codes_i, out, partials);
    loss_kernel<<<1, 256, 0, stream>>>(partials, out);
}

// Round 9
// 82.801 us; speedup vs baseline: 1.9252x; 1.1361x over previous
//
#include <hip/hip_runtime.h>
#include <hip/hip_bf16.h>

typedef __attribute__((ext_vector_type(8))) short short8;   // 8 bf16 = 4 VGPR
typedef __attribute__((ext_vector_type(4))) float f32x4;

// Problem dims (fixed by reference)
constexpr int Bb = 8;
constexpr int Dd = 64;
constexpr int Tt = 8192;
constexpr int Kk = 1024;
constexpr int BT = Bb * Tt;            // 65536 rows
constexpr int NTOT = Bb * Dd * Tt;     // 4194304 elements

// Output layout (float32): [codes BT][quantized NTOT][loss 1]
constexpr int OUT_Q_OFF = BT;
constexpr int OUT_LOSS_OFF = BT + NTOT;

// Workspace layout (bytes)
constexpr size_t WS_CODES_OFF = 0;                        // int32[BT]      256KB
constexpr size_t WS_PREC_OFF  = (size_t)BT * 4;           // float[K]       4KB
constexpr size_t WS_PART_OFF  = WS_PREC_OFF + 4096;       // float[256]     1KB
constexpr size_t WS_EH_OFF    = WS_PART_OFF + 4096;       // bf16[K*D] x3
constexpr size_t WS_EM_OFF    = WS_EH_OFF + (size_t)Kk * Dd * 2;
constexpr size_t WS_EL_OFF    = WS_EM_OFF + (size_t)Kk * Dd * 2;

// ---- bf16 helpers (RNE, matches numpy/jax) ----
__device__ inline ushort rne_bf16(float v) {
    unsigned u = __float_as_uint(v);
    return (ushort)((u + 0x7FFFu + ((u >> 16) & 1u)) >> 16);
}
__device__ inline float bf16f(ushort h) { return __uint_as_float(((unsigned)h) << 16); }

// ---------------- Kernel P: prec[k] = ||e_k||^2 (fp32, exact path) ----------------
__global__ void __launch_bounds__(256) prec_kernel(const float* __restrict__ cb,
                                                   float* __restrict__ prec) {
    int k = blockIdx.x * 256 + threadIdx.x;
    if (k < Kk) {
        const float4* row = reinterpret_cast<const float4*>(cb + (size_t)k * Dd);
        float s = 0.f;
#pragma unroll
        for (int i = 0; i < 16; ++i) {
            float4 v = row[i];
            s = fmaf(v.x, v.x, s); s = fmaf(v.y, v.y, s);
            s = fmaf(v.z, v.z, s); s = fmaf(v.w, v.w, s);
        }
        prec[k] = s;
    }
}

// ---------------- Kernel S: 3-way bf16 split of codebook ----------------
__global__ void __launch_bounds__(256) split_e_kernel(const float* __restrict__ cb,
                                                      ushort* __restrict__ eh,
                                                      ushort* __restrict__ em,
                                                      ushort* __restrict__ el) {
    int i = blockIdx.x * 256 + threadIdx.x;   // K*D = 65536 total
    float v = cb[i];
    ushort h = rne_bf16(v);  float hf = bf16f(h);
    float r1 = v - hf;       ushort m = rne_bf16(r1); float mf = bf16f(m);
    float r2 = r1 - mf;      ushort l = rne_bf16(r2);
    eh[i] = h; em[i] = m; el[i] = l;
}

// ---------------- Kernel A: fused split-MFMA GEMM + argmin ----------------
// Same numerics as round 8 (6-pass split MFMA, reference-order fp32 score,
// tie -> lowest k). Round-8 counters: LDS-bound (per-tile A re-reads ~38us,
// epilogue reduce 8.3M bank conflicts ~13us). This version:
//   - A fragments (3 planes x 2 dsteps x 4 rf = 24 short8) live in REGISTERS,
//     read from z_lds exactly once.
//   - B fragments load DIRECTLY from global (e stored [k][d]: fragment is a
//     contiguous 16B/lane read; codebook is L2-resident). No e_lds, no
//     barriers in the k-loop; next-tile B + esq manually prefetched.
//   - Final reduce: in-wave __shfl_xor(width=16) tree + 2KB cross-wave LDS.
constexpr int TM = 64;              // rows per block
constexpr int NKT = Kk / 64;        // 16 k-tiles

__global__ void __launch_bounds__(256, 2) mfma_argmin_kernel(
    const float* __restrict__ z,
    const ushort* __restrict__ eh, const ushort* __restrict__ em,
    const ushort* __restrict__ el,
    const float* __restrict__ prec, float* __restrict__ out,
    int* __restrict__ codes_i)
{
    // z tile, 3 planes, swizzled: [split][row][d], row stride 128B, byte ^= (row&7)<<4
    __shared__ __align__(16) ushort z_lds[3 * 64 * 64];   // 24 KB
    __shared__ float zsq_part[4][64];
    __shared__ float zsq_lds[64];
    __shared__ float red_v[4][64];
    __shared__ int   red_i[4][64];

    const int tid = threadIdx.x;
    const int lane = tid & 63;
    const int w = tid >> 6;                 // wave 0..3 -> k-slice w*16..+16
    const int row0 = blockIdx.x * TM;
    const int b = row0 >> 13;
    const int t0 = row0 & (Tt - 1);

    // ---- stage z: read [d][t] coalesced, 3-way split, write transposed+swizzled
    {
        const int tt = tid & 63;            // row within tile
        const int dg = tid >> 6;            // d-group: d = dg*16 .. +16
        const float* zp = z + (size_t)b * (Dd * Tt) + (size_t)(dg * 16) * Tt + (t0 + tt);
        float vals[16];
        float psum = 0.f;
#pragma unroll
        for (int i = 0; i < 16; ++i) {
            float v = zp[(size_t)i * Tt];
            vals[i] = v;
            psum = fmaf(v, v, psum);
        }
        zsq_part[dg][tt] = psum;
#pragma unroll
        for (int g = 0; g < 2; ++g) {
            short8 hv, mv, lv;
#pragma unroll
            for (int j = 0; j < 8; ++j) {
                float v = vals[g * 8 + j];
                ushort h = rne_bf16(v);  float hf = bf16f(h);
                float r1 = v - hf;       ushort m = rne_bf16(r1); float mf = bf16f(m);
                float r2 = r1 - mf;      ushort l = rne_bf16(r2);
                hv[j] = (short)h; mv[j] = (short)m; lv[j] = (short)l;
            }
            const int byte_in_row = dg * 32 + g * 16;     // d0*2
            const int sw = tt * 128 + (byte_in_row ^ ((tt & 7) << 4));
            *reinterpret_cast<short8*>((char*)z_lds + 0 * 8192 + sw) = hv;
            *reinterpret_cast<short8*>((char*)z_lds + 1 * 8192 + sw) = mv;
            *reinterpret_cast<short8*>((char*)z_lds + 2 * 8192 + sw) = lv;
        }
    }
    __syncthreads();
    if (tid < 64)
        zsq_lds[tid] = ((zsq_part[0][tid] + zsq_part[1][tid]) + zsq_part[2][tid]) + zsq_part[3][tid];
    __syncthreads();

    // ---- A fragments into registers (once). Same addresses as round 8's per-tile reads.
    short8 A[3][2][4];   // [plane][dstep][rf] — all indices compile-time after unroll
#pragma unroll
    for (int sA = 0; sA < 3; ++sA)
#pragma unroll
        for (int ds = 0; ds < 2; ++ds)
#pragma unroll
            for (int rf = 0; rf < 4; ++rf) {
                const int row = rf * 16 + (lane & 15);
                const int dby = ds * 64 + ((lane >> 4) * 16);
                A[sA][ds][rf] = *reinterpret_cast<const short8*>(
                    (char*)z_lds + sA * 8192 + row * 128 + (dby ^ ((row & 7) << 4)));
            }

    // per-lane row-set zsq: row = rf*16 + (lane>>4)*4 + j
    float zsq_r[16];
#pragma unroll
    for (int rf = 0; rf < 4; ++rf)
#pragma unroll
        for (int j = 0; j < 4; ++j)
            zsq_r[rf * 4 + j] = zsq_lds[rf * 16 + (lane >> 4) * 4 + j];

    float bestv[16];
    int   besti[16];
#pragma unroll
    for (int i = 0; i < 16; ++i) { bestv[i] = 3.4e38f; besti[i] = 0; }

    const int kl = lane & 15;
    const int d0 = (lane >> 4) * 8;

    // B fragment loads from global: plane p, dstep ds for k-tile kt
    short8 Bc[6];      // [p*2+ds]
    float esqc;
    {
        const size_t kg = (size_t)(w * 16 + kl);
        const size_t base = kg * 64 + d0;
        Bc[0] = *reinterpret_cast<const short8*>(eh + base);
        Bc[1] = *reinterpret_cast<const short8*>(eh + base + 32);
        Bc[2] = *reinterpret_cast<const short8*>(em + base);
        Bc[3] = *reinterpret_cast<const short8*>(em + base + 32);
        Bc[4] = *reinterpret_cast<const short8*>(el + base);
        Bc[5] = *reinterpret_cast<const short8*>(el + base + 32);
        esqc = prec[kg];
    }

    for (int kt = 0; kt < NKT; ++kt) {
        short8 Bn[6];
        float esqn = 0.f;
        if (kt + 1 < NKT) {
            const size_t kg = (size_t)((kt + 1) * 64 + w * 16 + kl);
            const size_t base = kg * 64 + d0;
            Bn[0] = *reinterpret_cast<const short8*>(eh + base);
            Bn[1] = *reinterpret_cast<const short8*>(eh + base + 32);
            Bn[2] = *reinterpret_cast<const short8*>(em + base);
            Bn[3] = *reinterpret_cast<const short8*>(em + base + 32);
            Bn[4] = *reinterpret_cast<const short8*>(el + base);
            Bn[5] = *reinterpret_cast<const short8*>(el + base + 32);
            esqn = prec[kg];
        }

        f32x4 acc[4];
#pragma unroll
        for (int rf = 0; rf < 4; ++rf) acc[rf] = (f32x4){0.f, 0.f, 0.f, 0.f};

        // pass order identical to round 8: per dstep: (zh,eh),(zh,em),(zh,el),(zm,eh),(zm,em),(zl,eh)
#pragma unroll
        for (int ds = 0; ds < 2; ++ds) {
#pragma unroll
            for (int rf = 0; rf < 4; ++rf)
                acc[rf] = __builtin_amdgcn_mfma_f32_16x16x32_bf16(A[0][ds][rf], Bc[0 * 2 + ds], acc[rf], 0, 0, 0);
#pragma unroll
            for (int rf = 0; rf < 4; ++rf)
                acc[rf] = __builtin_amdgcn_mfma_f32_16x16x32_bf16(A[0][ds][rf], Bc[1 * 2 + ds], acc[rf], 0, 0, 0);
#pragma unroll
            for (int rf = 0; rf < 4; ++rf)
                acc[rf] = __builtin_amdgcn_mfma_f32_16x16x32_bf16(A[0][ds][rf], Bc[2 * 2 + ds], acc[rf], 0, 0, 0);
#pragma unroll
            for (int rf = 0; rf < 4; ++rf)
                acc[rf] = __builtin_amdgcn_mfma_f32_16x16x32_bf16(A[1][ds][rf], Bc[0 * 2 + ds], acc[rf], 0, 0, 0);
#pragma unroll
            for (int rf = 0; rf < 4; ++rf)
                acc[rf] = __builtin_amdgcn_mfma_f32_16x16x32_bf16(A[1][ds][rf], Bc[1 * 2 + ds], acc[rf], 0, 0, 0);
#pragma unroll
            for (int rf = 0; rf < 4; ++rf)
                acc[rf] = __builtin_amdgcn_mfma_f32_16x16x32_bf16(A[2][ds][rf], Bc[0 * 2 + ds], acc[rf], 0, 0, 0);
        }

        // epilogue: score + running argmin (this lane's k = kglob for all 16 C-slots)
        const int kglob = kt * 64 + w * 16 + kl;
#pragma unroll
        for (int rf = 0; rf < 4; ++rf)
#pragma unroll
            for (int j = 0; j < 4; ++j) {
                const float t1 = zsq_r[rf * 4 + j] + esqc;       // round(zsq+esq)
                const float s = fmaf(-2.f, acc[rf][j], t1);      // round(t1-2dot)
                if (s < bestv[rf * 4 + j]) { bestv[rf * 4 + j] = s; besti[rf * 4 + j] = kglob; }
            }

        if (kt + 1 < NKT) {
#pragma unroll
            for (int i = 0; i < 6; ++i) Bc[i] = Bn[i];
            esqc = esqn;
        }
    }

    // ---- in-wave reduce over the 16 k-slots (lane&15) per row, tie -> lower k
#pragma unroll
    for (int i = 0; i < 16; ++i) {
#pragma unroll
        for (int m = 1; m < 16; m <<= 1) {
            const float ov = __shfl_xor(bestv[i], m, 16);
            const int   oi = __shfl_xor(besti[i], m, 16);
            if (ov < bestv[i] || (ov == bestv[i] && oi < besti[i])) {
                bestv[i] = ov; besti[i] = oi;
            }
        }
    }
    if ((lane & 15) == 0) {
#pragma unroll
        for (int rf = 0; rf < 4; ++rf)
#pragma unroll
            for (int j = 0; j < 4; ++j) {
                const int row = rf * 16 + (lane >> 4) * 4 + j;
                red_v[w][row] = bestv[rf * 4 + j];
                red_i[w][row] = besti[rf * 4 + j];
            }
    }
    __syncthreads();
    if (tid < 64) {
        float bv = red_v[0][tid];
        int   bi = red_i[0][tid];
#pragma unroll
        for (int s2 = 1; s2 < 4; ++s2) {
            const float v = red_v[s2][tid];
            const int   i = red_i[s2][tid];
            if (v < bv || (v == bv && i < bi)) { bv = v; bi = i; }
        }
        codes_i[row0 + tid] = bi;
        out[row0 + tid] = (float)bi;
    }
}

// ---------------- Kernel B: quantized + loss partials ----------------
__global__ void __launch_bounds__(256) quant_kernel(
    const float* __restrict__ z, const float* __restrict__ cb,
    const int* __restrict__ codes_i, float* __restrict__ out,
    float* __restrict__ partials)
{
    const int row = blockIdx.x * 256 + threadIdx.x;  // grid = 256 blocks
    const int b = row >> 13;
    const int t = row & (Tt - 1);
    const int code = codes_i[row];
    const float4* crow = reinterpret_cast<const float4*>(cb + (size_t)code * Dd);
    const float* zbase = z + (size_t)b * (Dd * Tt) + t;
    float* obase = out + OUT_Q_OFF + (size_t)b * (Dd * Tt) + t;

    float acc = 0.f;
#pragma unroll
    for (int d4 = 0; d4 < 16; ++d4) {
        float4 v = crow[d4];
        float vv[4] = {v.x, v.y, v.z, v.w};
#pragma unroll
        for (int j = 0; j < 4; ++j) {
            const int d = d4 * 4 + j;
            const float zv = zbase[(size_t)d * Tt];
            const float diff = vv[j] - zv;
            acc = fmaf(diff, diff, acc);
            obase[(size_t)d * Tt] = vv[j];
        }
    }

    __shared__ float red[256];
    red[threadIdx.x] = acc;
    __syncthreads();
#pragma unroll
    for (int s = 128; s > 0; s >>= 1) {
        if (threadIdx.x < s) red[threadIdx.x] += red[threadIdx.x + s];
        __syncthreads();
    }
    if (threadIdx.x == 0) partials[blockIdx.x] = red[0];
}

// ---------------- Kernel C: final loss reduce ----------------
__global__ void __launch_bounds__(256) loss_kernel(const float* __restrict__ partials,
                                                   float* __restrict__ out) {
    __shared__ float red[256];
    red[threadIdx.x] = partials[threadIdx.x];  // exactly 256 partials
    __syncthreads();
#pragma unroll
    for (int s = 128; s > 0; s >>= 1) {
        if (threadIdx.x < s) red[threadIdx.x] += red[threadIdx.x + s];
        __syncthreads();
    }
    if (threadIdx.x == 0)
        out[OUT_LOSS_OFF] = red[0] * (1.0f / (float)NTOT);
}

extern "C" void kernel_launch(void* const* d_in, const int* in_sizes, int n_in,
                              void* d_out, int out_size, void* d_ws, size_t ws_size,
                              hipStream_t stream) {
    const float* z = (const float*)d_in[0];
    const float* cb = (const float*)d_in[1];
    float* out = (float*)d_out;

    char* ws = (char*)d_ws;
    int* codes_i = (int*)(ws + WS_CODES_OFF);
    float* prec = (float*)(ws + WS_PREC_OFF);
    float* partials = (float*)(ws + WS_PART_OFF);
    ushort* eh = (ushort*)(ws + WS_EH_OFF);
    ushort* em = (ushort*)(ws + WS_EM_OFF);
    ushort* el = (ushort*)(ws + WS_EL_OFF);

    prec_kernel<<<(Kk + 255) / 256, 256, 0, stream>>>(cb, prec);
    split_e_kernel<<<(Kk * Dd) / 256, 256, 0, stream>>>(cb, eh, em, el);
    mfma_argmin_kernel<<<BT / TM, 256, 0, stream>>>(z, eh, em, el, prec, out, codes_i);
    quant_kernel<<<BT / 256, 256, 0, stream>>>(z, cb, codes_i, out, partials);
    loss_kernel<<<1, 256, 0, stream>>>(partials, out);
}